// Round 1
// baseline (2410.014 us; speedup 1.0000x reference)
//
#include <hip/hip_runtime.h>
#include <math.h>

// GNNMLP: G=131072 groups x 6 agents x 64 features.
// K1: fused SAGE-pool conv1(+tanh) + conv2 + mean  -> res[G,64] in d_ws
// K2: per-type 3x relu-MLP + 64->2 head + tanh     -> out[G,6,2]
//
// Layout choice: lane = output feature j (0..63), wave = one group at a time.
// Conv weights (6 x 64x64 fp32 = 96 KB) live in LDS, read as W[k*64+j]
// (2-way bank aliasing = free). Activation broadcasts go through per-wave
// private LDS scratch as float4 (same-address b128 broadcast).
// mean_i(h_i @ Ws2) == (mean_i h_i) @ Ws2  -- mean commutes with linear map.

#define G_TOTAL 131072

__device__ __forceinline__ float fast_tanh(float x) {
    // tanh(x) = 1 - 2/(e^{2x}+1); robust at +-inf, rel err ~1e-6
    float e = __expf(2.0f * x);
    return 1.0f - 2.0f / (e + 1.0f);
}

// ---------------- Kernel 1: conv1 + conv2 + mean ----------------
// block = 1024 (16 waves), grid = 256 (1 block/CU; LDS 132 KB), 32 groups/wave
#define K1_WAVES 16
#define K1_GPW   32

__global__ __launch_bounds__(1024, 1)
void conv_fused(const float* __restrict__ obs,
                const float* __restrict__ Wp1, const float* __restrict__ bp1,
                const float* __restrict__ Ws1, const float* __restrict__ Wn1,
                const float* __restrict__ b1,
                const float* __restrict__ Wp2, const float* __restrict__ bp2,
                const float* __restrict__ Ws2, const float* __restrict__ Wn2,
                const float* __restrict__ b2,
                float* __restrict__ res)
{
    __shared__ float wl[6 * 4096];          // Wp1|Ws1|Wn1|Wp2|Ws2|Wn2  (96 KB)
    __shared__ float sc[K1_WAVES][576];     // per-wave: rows[0..383] n1[384] hbar[448] n2[512]

    const int tid = threadIdx.x;
    for (int idx = tid; idx < 4096; idx += 1024) {
        wl[idx]         = Wp1[idx];
        wl[4096  + idx] = Ws1[idx];
        wl[8192  + idx] = Wn1[idx];
        wl[12288 + idx] = Wp2[idx];
        wl[16384 + idx] = Ws2[idx];
        wl[20480 + idx] = Wn2[idx];
    }
    __syncthreads();

    const int w = tid >> 6;
    const int j = tid & 63;
    float* sw = sc[w];

    const float bp1j = bp1[j], b1j = b1[j], bp2j = bp2[j], b2j = b2[j];
    const int g0 = (blockIdx.x * K1_WAVES + w) * K1_GPW;

    for (int it = 0; it < K1_GPW; ++it) {
        const int g = g0 + it;
        const float* og = obs + (size_t)g * 384;

        // stage obs rows (coalesced)
        #pragma unroll
        for (int i = 0; i < 6; ++i) sw[i * 64 + j] = og[i * 64 + j];
        __syncthreads();

        // phase A: p_i = obs_i @ Wp1 + bp1 ; t_i = obs_i @ Ws1   (shared obs bcast)
        float p[6], t[6];
        #pragma unroll
        for (int i = 0; i < 6; ++i) { p[i] = bp1j; t[i] = 0.f; }
        #pragma unroll
        for (int k0 = 0; k0 < 64; k0 += 4) {
            float wp[4], ws[4];
            #pragma unroll
            for (int c = 0; c < 4; ++c) {
                wp[c] = wl[(k0 + c) * 64 + j];
                ws[c] = wl[4096 + (k0 + c) * 64 + j];
            }
            #pragma unroll
            for (int i = 0; i < 6; ++i) {
                const float4 o = *(const float4*)&sw[i * 64 + k0];
                p[i] = fmaf(o.x, wp[0], fmaf(o.y, wp[1], fmaf(o.z, wp[2], fmaf(o.w, wp[3], p[i]))));
                t[i] = fmaf(o.x, ws[0], fmaf(o.y, ws[1], fmaf(o.z, ws[2], fmaf(o.w, ws[3], t[i]))));
            }
        }

        // neigh1 = max_i relu(p_i)   (>=0, so fold relu into max with 0-init)
        float n1 = 0.f;
        #pragma unroll
        for (int i = 0; i < 6; ++i) n1 = fmaxf(n1, p[i]);
        sw[384 + j] = n1;
        __syncthreads();

        // c = neigh1 @ Wn1 + b1
        float cacc = b1j;
        #pragma unroll
        for (int k0 = 0; k0 < 64; k0 += 4) {
            float wn[4];
            #pragma unroll
            for (int c = 0; c < 4; ++c) wn[c] = wl[8192 + (k0 + c) * 64 + j];
            const float4 nb = *(const float4*)&sw[384 + k0];
            cacc = fmaf(nb.x, wn[0], fmaf(nb.y, wn[1], fmaf(nb.z, wn[2], fmaf(nb.w, wn[3], cacc))));
        }

        // h_i = tanh(t_i + c); hbar = mean_i h_i ; h rows overwrite obs scratch
        float hbar = 0.f;
        #pragma unroll
        for (int i = 0; i < 6; ++i) {
            const float h = fast_tanh(t[i] + cacc);
            hbar += h;
            sw[i * 64 + j] = h;
        }
        hbar *= (1.0f / 6.0f);
        sw[448 + j] = hbar;
        __syncthreads();

        // conv2 pool: q_i = h_i @ Wp2 + bp2 -> neigh2 = max_i relu(q_i)
        float q[6];
        #pragma unroll
        for (int i = 0; i < 6; ++i) q[i] = bp2j;
        #pragma unroll
        for (int k0 = 0; k0 < 64; k0 += 4) {
            float wq[4];
            #pragma unroll
            for (int c = 0; c < 4; ++c) wq[c] = wl[12288 + (k0 + c) * 64 + j];
            #pragma unroll
            for (int i = 0; i < 6; ++i) {
                const float4 hb = *(const float4*)&sw[i * 64 + k0];
                q[i] = fmaf(hb.x, wq[0], fmaf(hb.y, wq[1], fmaf(hb.z, wq[2], fmaf(hb.w, wq[3], q[i]))));
            }
        }
        float n2 = 0.f;
        #pragma unroll
        for (int i = 0; i < 6; ++i) n2 = fmaxf(n2, q[i]);
        sw[512 + j] = n2;
        __syncthreads();

        // res = hbar @ Ws2 + neigh2 @ Wn2 + b2
        float r = b2j;
        #pragma unroll
        for (int k0 = 0; k0 < 64; k0 += 4) {
            float w2s[4], w2n[4];
            #pragma unroll
            for (int c = 0; c < 4; ++c) {
                w2s[c] = wl[16384 + (k0 + c) * 64 + j];
                w2n[c] = wl[20480 + (k0 + c) * 64 + j];
            }
            const float4 hb = *(const float4*)&sw[448 + k0];
            const float4 nb = *(const float4*)&sw[512 + k0];
            r = fmaf(hb.x, w2s[0], fmaf(hb.y, w2s[1], fmaf(hb.z, w2s[2], fmaf(hb.w, w2s[3], r))));
            r = fmaf(nb.x, w2n[0], fmaf(nb.y, w2n[1], fmaf(nb.z, w2n[2], fmaf(nb.w, w2n[3], r))));
        }
        res[(size_t)g * 64 + j] = r;
    }
}

// ---------------- Kernel 2: per-type MLP ----------------
// block = 256 (4 waves). Each wave: one (type, 32-group slice) task.
// MLP weight columns resident in VGPRs (3 x 64 = 192 regs), amortized over 32 groups.
#define K2_GPW 32

__global__ void mlp_kernel(const float* __restrict__ res,
                           const float* __restrict__ MW1, const float* __restrict__ Mb1,
                           const float* __restrict__ MW2, const float* __restrict__ Mb2,
                           const float* __restrict__ MW3, const float* __restrict__ Mb3,
                           const float* __restrict__ MW4, const float* __restrict__ Mb4,
                           float* __restrict__ out)
{
    __shared__ float sc[4][128];   // per-wave ping-pong broadcast buffers
    const int tid = threadIdx.x;
    const int w = tid >> 6;
    const int j = tid & 63;
    float* sA = sc[w];
    float* sB = sc[w] + 64;

    const int wid   = blockIdx.x * 4 + w;
    const int type  = wid & 1;
    const int gbase = (wid >> 1) * K2_GPW;
    const int toff  = type * 4096;

    float w1[64], w2[64], w3[64];
    #pragma unroll
    for (int k = 0; k < 64; ++k) {
        w1[k] = MW1[toff + k * 64 + j];
        w2[k] = MW2[toff + k * 64 + j];
        w3[k] = MW3[toff + k * 64 + j];
    }
    const float mb1j = Mb1[type * 64 + j];
    const float mb2j = Mb2[type * 64 + j];
    const float mb3j = Mb3[type * 64 + j];
    const float w4o0 = MW4[type * 128 + j * 2];
    const float w4o1 = MW4[type * 128 + j * 2 + 1];
    const float mb40 = Mb4[type * 2];
    const float mb41 = Mb4[type * 2 + 1];

    for (int it = 0; it < K2_GPW; ++it) {
        const int g = gbase + it;
        sA[j] = res[(size_t)g * 64 + j];
        __syncthreads();

        float x1 = mb1j;
        #pragma unroll
        for (int k0 = 0; k0 < 64; k0 += 4) {
            const float4 xb = *(const float4*)&sA[k0];
            x1 = fmaf(xb.x, w1[k0], fmaf(xb.y, w1[k0+1], fmaf(xb.z, w1[k0+2], fmaf(xb.w, w1[k0+3], x1))));
        }
        x1 = fmaxf(x1, 0.f);
        sB[j] = x1;
        __syncthreads();

        float x2 = mb2j;
        #pragma unroll
        for (int k0 = 0; k0 < 64; k0 += 4) {
            const float4 xb = *(const float4*)&sB[k0];
            x2 = fmaf(xb.x, w2[k0], fmaf(xb.y, w2[k0+1], fmaf(xb.z, w2[k0+2], fmaf(xb.w, w2[k0+3], x2))));
        }
        x2 = fmaxf(x2, 0.f);
        sA[j] = x2;
        __syncthreads();

        float x3 = mb3j;
        #pragma unroll
        for (int k0 = 0; k0 < 64; k0 += 4) {
            const float4 xb = *(const float4*)&sA[k0];
            x3 = fmaf(xb.x, w3[k0], fmaf(xb.y, w3[k0+1], fmaf(xb.z, w3[k0+2], fmaf(xb.w, w3[k0+3], x3))));
        }
        x3 = fmaxf(x3, 0.f);

        // head: out_o = tanh(sum_k x3[k] * MW4[k][o] + Mb4[o]) via wave butterfly
        float po0 = x3 * w4o0;
        float po1 = x3 * w4o1;
        #pragma unroll
        for (int off = 32; off > 0; off >>= 1) {
            po0 += __shfl_xor(po0, off, 64);
            po1 += __shfl_xor(po1, off, 64);
        }
        const float o0 = fast_tanh(po0 + mb40);
        const float o1 = fast_tanh(po1 + mb41);

        // out[g, a, o]: agents 0..4 <- type0, agent 5 <- type1
        if (type == 0) {
            if (j < 10) out[(size_t)g * 12 + j] = (j & 1) ? o1 : o0;
        } else {
            if (j < 2)  out[(size_t)g * 12 + 10 + j] = j ? o1 : o0;
        }
        __syncthreads();
    }
}

extern "C" void kernel_launch(void* const* d_in, const int* in_sizes, int n_in,
                              void* d_out, int out_size, void* d_ws, size_t ws_size,
                              hipStream_t stream)
{
    const float* obs = (const float*)d_in[0];
    const float* Wp1 = (const float*)d_in[1];
    const float* bp1 = (const float*)d_in[2];
    const float* Ws1 = (const float*)d_in[3];
    const float* Wn1 = (const float*)d_in[4];
    const float* b1  = (const float*)d_in[5];
    const float* Wp2 = (const float*)d_in[6];
    const float* bp2 = (const float*)d_in[7];
    const float* Ws2 = (const float*)d_in[8];
    const float* Wn2 = (const float*)d_in[9];
    const float* b2  = (const float*)d_in[10];
    const float* MW1 = (const float*)d_in[11];
    const float* Mb1 = (const float*)d_in[12];
    const float* MW2 = (const float*)d_in[13];
    const float* Mb2 = (const float*)d_in[14];
    const float* MW3 = (const float*)d_in[15];
    const float* Mb3 = (const float*)d_in[16];
    const float* MW4 = (const float*)d_in[17];
    const float* Mb4 = (const float*)d_in[18];

    float* res = (float*)d_ws;      // G*64 fp32 = 33.5 MB scratch
    float* out = (float*)d_out;

    // K1: 256 blocks x 1024 threads, 16 waves x 32 groups = 131072 groups
    hipLaunchKernelGGL(conv_fused, dim3(256), dim3(1024), 0, stream,
                       obs, Wp1, bp1, Ws1, Wn1, b1, Wp2, bp2, Ws2, Wn2, b2, res);
    // K2: 2048 blocks x 256 threads; 8192 wave-tasks = 2 types x 4096 slices
    hipLaunchKernelGGL(mlp_kernel, dim3(2048), dim3(256), 0, stream,
                       res, MW1, Mb1, MW2, Mb2, MW3, Mb3, MW4, Mb4, out);
}

// Round 2
// 678.304 us; speedup vs baseline: 3.5530x; 3.5530x over previous
//
#include <hip/hip_runtime.h>
#include <math.h>

// GNNMLP fused single kernel. G=131072 groups x 6 agents x 64 feat.
// Layout: block = 256 thr = 4 waves; block processes 64 groups per batch.
//   lane (0..63)  = group within batch
//   wave (0..3)   = 16-wide output-feature slice (j = w*16 + jj, jj unrolled)
// Weights: wave-uniform indices -> scalar s_load broadcast (no LDS, no VGPR cost).
// Activations: per-(group,j) values live in 16 named VGPRs per lane; matmul
// inputs stream from LDS slots (stride 68 floats: 16B-aligned, conflict-free
// 8-beat b128). All per-lane arrays are constant-indexed (fully unrolled j) --
// avoids the R1 scratch-spill disaster (VGPR_Count=64 + 3GB spill traffic).
// mean commutes with conv2's self-linear: mean_i(h_i)@Ws2 replaces 6 matmuls.

#define STRIDE 68          // 64 + 4 pad: keeps 16B alignment, breaks bank cycle
#define NB 2               // batches (of 64 groups) per block

__device__ __forceinline__ float fast_tanh(float x) {
    float e = __expf(2.0f * x);
    return 1.0f - 2.0f / (e + 1.0f);
}

// acc[jj] += sum_k Xs[l*STRIDE + k] * W[k*64 + w16 + jj]
// W reads are wave-uniform -> s_load; Xs reads are lane-divergent b128.
__device__ __forceinline__ void mm16(float (&acc)[16], const float* Xs, int lb,
                                     const float* __restrict__ W, int w16)
{
    #pragma unroll 2
    for (int k = 0; k < 64; k += 4) {
        const float4 xv = *(const float4*)(Xs + lb + k);
        const float* wr = W + k * 64 + w16;
        #pragma unroll
        for (int jj = 0; jj < 16; ++jj) acc[jj] = fmaf(xv.x, wr[jj],       acc[jj]);
        #pragma unroll
        for (int jj = 0; jj < 16; ++jj) acc[jj] = fmaf(xv.y, wr[64 + jj],  acc[jj]);
        #pragma unroll
        for (int jj = 0; jj < 16; ++jj) acc[jj] = fmaf(xv.z, wr[128 + jj], acc[jj]);
        #pragma unroll
        for (int jj = 0; jj < 16; ++jj) acc[jj] = fmaf(xv.w, wr[192 + jj], acc[jj]);
    }
}

// write this wave's 16-feature slice for lane l into a slot (4x b128, aligned)
__device__ __forceinline__ void put16(float* slot, int lb, int w16, const float (&v)[16])
{
    #pragma unroll
    for (int c = 0; c < 4; ++c)
        *(float4*)(slot + lb + w16 + 4 * c) = make_float4(v[4*c], v[4*c+1], v[4*c+2], v[4*c+3]);
}

// stage obs row i of 64 groups into slot (coalesced global, 8-beat LDS writes)
__device__ __forceinline__ void stageX(float* slot, const float* __restrict__ obs,
                                       int g0, int i, int t)
{
    #pragma unroll
    for (int r = 0; r < 4; ++r) {
        const int m = t + 256 * r;          // 0..1023 float4s
        const int g = m >> 4, q = m & 15;
        const float4 v = *(const float4*)(obs + (size_t)(g0 + g) * 384 + i * 64 + q * 4);
        *(float4*)(slot + g * STRIDE + q * 4) = v;
    }
}

__global__ __launch_bounds__(256)
void gnn_fused(const float* __restrict__ obs,
               const float* __restrict__ Wp1, const float* __restrict__ bp1,
               const float* __restrict__ Ws1, const float* __restrict__ Wn1,
               const float* __restrict__ b1,
               const float* __restrict__ Wp2, const float* __restrict__ bp2,
               const float* __restrict__ Ws2, const float* __restrict__ Wn2,
               const float* __restrict__ b2,
               const float* __restrict__ MW1, const float* __restrict__ Mb1,
               const float* __restrict__ MW2, const float* __restrict__ Mb2,
               const float* __restrict__ MW3, const float* __restrict__ Mb3,
               const float* __restrict__ MW4, const float* __restrict__ Mb4,
               float* __restrict__ out)
{
    __shared__ float A[64 * STRIDE];
    __shared__ float B[64 * STRIDE];
    __shared__ float Ost[64 * 12];

    const int t   = threadIdx.x;
    const int w   = __builtin_amdgcn_readfirstlane(t >> 6);  // force wave-uniform
    const int l   = t & 63;
    const int w16 = w * 16;
    const int lb  = l * STRIDE;

    for (int b = 0; b < NB; ++b) {
        const int g0 = (blockIdx.x * NB + b) * 64;

        // ---- conv1 pass 1: n1[j] = max_i relu(obs_i @ Wp1 + bp1) ----
        float n1[16];
        #pragma unroll
        for (int jj = 0; jj < 16; ++jj) n1[jj] = 0.f;
        for (int i = 0; i < 6; ++i) {
            __syncthreads();                 // slot A free (prev readers done)
            stageX(A, obs, g0, i, t);
            __syncthreads();
            float p[16];
            #pragma unroll
            for (int jj = 0; jj < 16; ++jj) p[jj] = bp1[w16 + jj];
            mm16(p, A, lb, Wp1, w16);
            #pragma unroll
            for (int jj = 0; jj < 16; ++jj) n1[jj] = fmaxf(n1[jj], p[jj]);
        }

        // ---- c = n1 @ Wn1 + b1 ----
        __syncthreads();
        put16(B, lb, w16, n1);
        __syncthreads();
        float c[16];
        #pragma unroll
        for (int jj = 0; jj < 16; ++jj) c[jj] = b1[w16 + jj];
        mm16(c, B, lb, Wn1, w16);

        // ---- conv1 pass 2 + conv2 pool, per row ----
        float hbar[16], n2[16];
        #pragma unroll
        for (int jj = 0; jj < 16; ++jj) { hbar[jj] = 0.f; n2[jj] = 0.f; }
        for (int i = 0; i < 6; ++i) {
            __syncthreads();
            stageX(A, obs, g0, i, t);        // re-read obs (L2/L3-hot)
            __syncthreads();
            float h[16];
            #pragma unroll
            for (int jj = 0; jj < 16; ++jj) h[jj] = 0.f;
            mm16(h, A, lb, Ws1, w16);        // t_i = obs_i @ Ws1
            #pragma unroll
            for (int jj = 0; jj < 16; ++jj) {
                h[jj] = fast_tanh(h[jj] + c[jj]);
                hbar[jj] += h[jj];
            }
            __syncthreads();                 // slot B free (prev q readers done)
            put16(B, lb, w16, h);
            __syncthreads();
            float q[16];
            #pragma unroll
            for (int jj = 0; jj < 16; ++jj) q[jj] = bp2[w16 + jj];
            mm16(q, B, lb, Wp2, w16);        // q_i = h_i @ Wp2 + bp2
            #pragma unroll
            for (int jj = 0; jj < 16; ++jj) n2[jj] = fmaxf(n2[jj], q[jj]);
        }
        #pragma unroll
        for (int jj = 0; jj < 16; ++jj) hbar[jj] *= (1.0f / 6.0f);

        // ---- res = hbar @ Ws2 + n2 @ Wn2 + b2 ----
        __syncthreads();
        put16(A, lb, w16, hbar);
        __syncthreads();
        float r[16];
        #pragma unroll
        for (int jj = 0; jj < 16; ++jj) r[jj] = b2[w16 + jj];
        mm16(r, A, lb, Ws2, w16);
        __syncthreads();
        put16(B, lb, w16, n2);
        __syncthreads();
        mm16(r, B, lb, Wn2, w16);

        // ---- per-type MLP (type0 -> agents 0..4, type1 -> agent 5) ----
        for (int ty = 0; ty < 2; ++ty) {
            const int toff = ty * 4096, t64 = ty * 64;
            __syncthreads();
            put16(A, lb, w16, r);
            __syncthreads();
            float x1[16];
            #pragma unroll
            for (int jj = 0; jj < 16; ++jj) x1[jj] = Mb1[t64 + w16 + jj];
            mm16(x1, A, lb, MW1 + toff, w16);
            #pragma unroll
            for (int jj = 0; jj < 16; ++jj) x1[jj] = fmaxf(x1[jj], 0.f);
            __syncthreads();
            put16(B, lb, w16, x1);
            __syncthreads();
            float x2[16];
            #pragma unroll
            for (int jj = 0; jj < 16; ++jj) x2[jj] = Mb2[t64 + w16 + jj];
            mm16(x2, B, lb, MW2 + toff, w16);
            #pragma unroll
            for (int jj = 0; jj < 16; ++jj) x2[jj] = fmaxf(x2[jj], 0.f);
            __syncthreads();
            put16(A, lb, w16, x2);
            __syncthreads();
            float x3[16];
            #pragma unroll
            for (int jj = 0; jj < 16; ++jj) x3[jj] = Mb3[t64 + w16 + jj];
            mm16(x3, A, lb, MW3 + toff, w16);
            #pragma unroll
            for (int jj = 0; jj < 16; ++jj) x3[jj] = fmaxf(x3[jj], 0.f);
            __syncthreads();
            put16(B, lb, w16, x3);
            __syncthreads();

            // head (all waves compute redundantly; wave 0 stages the output)
            float a0 = Mb4[ty * 2], a1 = Mb4[ty * 2 + 1];
            #pragma unroll 2
            for (int k = 0; k < 64; k += 4) {
                const float4 xv = *(const float4*)(B + lb + k);
                const float* w4 = MW4 + ty * 128 + k * 2;
                a0 = fmaf(xv.x, w4[0], a0);  a1 = fmaf(xv.x, w4[1], a1);
                a0 = fmaf(xv.y, w4[2], a0);  a1 = fmaf(xv.y, w4[3], a1);
                a0 = fmaf(xv.z, w4[4], a0);  a1 = fmaf(xv.z, w4[5], a1);
                a0 = fmaf(xv.w, w4[6], a0);  a1 = fmaf(xv.w, w4[7], a1);
            }
            a0 = fast_tanh(a0);
            a1 = fast_tanh(a1);
            if (w == 0) {
                if (ty == 0) {
                    #pragma unroll
                    for (int ag = 0; ag < 5; ++ag) {
                        Ost[l * 12 + ag * 2]     = a0;
                        Ost[l * 12 + ag * 2 + 1] = a1;
                    }
                } else {
                    Ost[l * 12 + 10] = a0;
                    Ost[l * 12 + 11] = a1;
                }
            }
        }

        // ---- store out[g0..g0+63][6][2] ----
        __syncthreads();
        if (t < 192) {
            const int g = t / 3, q = t % 3;
            *(float4*)(out + (size_t)(g0 + g) * 12 + q * 4) =
                *(const float4*)(Ost + g * 12 + q * 4);
        }
    }
}

extern "C" void kernel_launch(void* const* d_in, const int* in_sizes, int n_in,
                              void* d_out, int out_size, void* d_ws, size_t ws_size,
                              hipStream_t stream)
{
    const float* obs = (const float*)d_in[0];
    const float* Wp1 = (const float*)d_in[1];
    const float* bp1 = (const float*)d_in[2];
    const float* Ws1 = (const float*)d_in[3];
    const float* Wn1 = (const float*)d_in[4];
    const float* b1  = (const float*)d_in[5];
    const float* Wp2 = (const float*)d_in[6];
    const float* bp2 = (const float*)d_in[7];
    const float* Ws2 = (const float*)d_in[8];
    const float* Wn2 = (const float*)d_in[9];
    const float* b2  = (const float*)d_in[10];
    const float* MW1 = (const float*)d_in[11];
    const float* Mb1 = (const float*)d_in[12];
    const float* MW2 = (const float*)d_in[13];
    const float* Mb2 = (const float*)d_in[14];
    const float* MW3 = (const float*)d_in[15];
    const float* Mb3 = (const float*)d_in[16];
    const float* MW4 = (const float*)d_in[17];
    const float* Mb4 = (const float*)d_in[18];
    float* out = (float*)d_out;

    // 131072 groups / 64 per batch / NB=2 batches per block = 1024 blocks
    hipLaunchKernelGGL(gnn_fused, dim3(1024), dim3(256), 0, stream,
                       obs, Wp1, bp1, Ws1, Wn1, b1, Wp2, bp2, Ws2, Wn2, b2,
                       MW1, Mb1, MW2, Mb2, MW3, Mb3, MW4, Mb4, out);
}

// Round 3
// 424.554 us; speedup vs baseline: 5.6766x; 1.5977x over previous
//
#include <hip/hip_runtime.h>
#include <math.h>

// GNNMLP via f16 MFMA. G=131072 groups x 6 agents x 64 feats.
// prep_weights: fp32 weights -> f16, transposed (B[k][n] with k contiguous per
//   column) + XOR-octet swizzle (conflict-free b128 B-frag reads) -> img in d_ws.
// gnn_mfma: block=512 (8 waves, 1 block/CU, 137 KB LDS). Each wave owns batches
//   of 16 groups. M-supertile = 6 agent-tiles x 16 groups so agent-pooling
//   (max / mean) is per-lane elementwise across C-fragments. Group-level
//   matmuls (M=16) round-trip C->LDS->A via a wave-PRIVATE slab (stride 68
//   f32): no __syncthreads in the batch loop, lgkmcnt ordering only.
// MFMA 16x16x32 f16 layouts (m89/m120-verified family):
//   A[m][k]: m=lane&15, k=(lane>>4)*8+j     B[k][n]: n=lane&15, k=(lane>>4)*8+j
//   C/D:     col=lane&15, row=(lane>>4)*4+reg

typedef _Float16 f16;
typedef _Float16 half8_t __attribute__((ext_vector_type(8)));
typedef float    float4_t __attribute__((ext_vector_type(4)));

#define NW 8            // waves per block
#define NB 4            // batches (16 groups) per wave
#define SLABF (16*68)   // wave slab: 16 rows x 68 f32 (pad 4: 2-way banks = free)
#define IMG_HALFS 51200 // 12*4096 + 2*1024

__device__ __forceinline__ int swz_off(int n, int k) {
    // matrix-local half offset for logical element (n, k): row n (64 halfs),
    // octet (k>>3) XOR'd with n&7, j = k&7 contiguous.
    return n * 64 + (((k >> 3) ^ (n & 7)) << 3) + (k & 7);
}

__device__ __forceinline__ float fast_tanh(float x) {
    float e = __expf(2.0f * x);
    return 1.0f - 2.0f / (e + 1.0f);
}

__device__ __forceinline__ float4_t max4(float4_t a, float4_t b) {
    float4_t r;
    r[0] = fmaxf(a[0], b[0]); r[1] = fmaxf(a[1], b[1]);
    r[2] = fmaxf(a[2], b[2]); r[3] = fmaxf(a[3], b[3]);
    return r;
}

__device__ __forceinline__ float4_t bcast4(float v) {
    float4_t r; r[0] = v; r[1] = v; r[2] = v; r[3] = v; return r;
}

// ---------------- prep: build f16 swizzled weight image in d_ws ----------------
__global__ void prep_weights(const float* __restrict__ Wp1, const float* __restrict__ Ws1,
                             const float* __restrict__ Wn1, const float* __restrict__ Wp2,
                             const float* __restrict__ Ws2, const float* __restrict__ Wn2,
                             const float* __restrict__ MW1, const float* __restrict__ MW2,
                             const float* __restrict__ MW3, const float* __restrict__ MW4,
                             f16* __restrict__ img)
{
    const int m = blockIdx.x;
    const int tid = threadIdx.x;
    if (m < 12) {
        const float* src;
        switch (m) {
            case 0: src = Wp1; break;  case 1: src = Ws1; break;
            case 2: src = Wn1; break;  case 3: src = Wp2; break;
            case 4: src = Ws2; break;  case 5: src = Wn2; break;
            case 6: src = MW1; break;  case 7: src = MW2; break;
            case 8: src = MW3; break;  case 9: src = MW1 + 4096; break;
            case 10: src = MW2 + 4096; break; default: src = MW3 + 4096; break;
        }
        for (int e = tid; e < 4096; e += 256) {
            const int k = e >> 6, n = e & 63;           // src is W[k][n] row-major
            img[m * 4096 + swz_off(n, k)] = (f16)src[e];
        }
    } else {
        // head B image: ty0 cols 0..9 = MW4[0][k][n&1] (agents 0..4 replicated),
        // ty1 cols 10,11 = MW4[1][k][n&1]; all other cols ZERO (C-chaining).
        for (int e = tid; e < 2048; e += 256) {
            const int ty = e >> 10, rem = e & 1023;
            const int n = rem >> 6, k = rem & 63;
            float v = 0.f;
            if (ty == 0) { if (n < 10) v = MW4[k * 2 + (n & 1)]; }
            else         { if (n == 10 || n == 11) v = MW4[128 + k * 2 + (n & 1)]; }
            img[12 * 4096 + ty * 1024 + swz_off(n, k)] = (f16)v;
        }
    }
}

// ---------------- main fused kernel ----------------
__global__ __launch_bounds__(512, 2)
void gnn_mfma(const float* __restrict__ obs, const f16* __restrict__ img,
              const float* __restrict__ bp1, const float* __restrict__ b1,
              const float* __restrict__ bp2, const float* __restrict__ b2,
              const float* __restrict__ Mb1, const float* __restrict__ Mb2,
              const float* __restrict__ Mb3, const float* __restrict__ Mb4,
              float* __restrict__ out)
{
    __shared__ __align__(16) unsigned char smem[IMG_HALFS * 2 + NW * SLABF * 4];
    f16* ldsW = (f16*)smem;

    const int tid = threadIdx.x;
    // one-time: weight image -> LDS (L2/L3-hot, 256 blocks read same 100 KB)
    for (int i = tid; i < IMG_HALFS / 8; i += 512)
        ((float4_t*)smem)[i] = ((const float4_t*)img)[i];
    __syncthreads();

    const int w    = __builtin_amdgcn_readfirstlane(tid >> 6);
    const int l    = tid & 63;
    const int col  = l & 15;
    const int quad = l >> 4;
    float* slab = (float*)(smem + IMG_HALFS * 2) + w * SLABF;

    // B-frag from LDS: matrix-base (halfs), Ntile nt, Kfrag kf
    auto loadB = [&](int baseH, int nt, int kf) -> half8_t {
        const int n = nt * 16 + col;
        return *(const half8_t*)(ldsW + baseH + n * 64 + ((((kf * 4 + quad) ^ (n & 7))) << 3));
    };
    // A-frag from wave slab (f32 -> f16): rows m=col, k = kf*32+quad*8+j
    auto loadA = [&](int kf) -> half8_t {
        const float4_t x = *(const float4_t*)(slab + col * 68 + kf * 32 + quad * 8);
        const float4_t y = *(const float4_t*)(slab + col * 68 + kf * 32 + quad * 8 + 4);
        half8_t r;
        r[0] = (f16)x[0]; r[1] = (f16)x[1]; r[2] = (f16)x[2]; r[3] = (f16)x[3];
        r[4] = (f16)y[0]; r[5] = (f16)y[1]; r[6] = (f16)y[2]; r[7] = (f16)y[3];
        return r;
    };
    // C-frag -> slab (row g = quad*4+r, feature nt*16+col)
    auto storeC = [&](const float4_t v, int nt) {
        #pragma unroll
        for (int r = 0; r < 4; ++r)
            slab[(quad * 4 + r) * 68 + nt * 16 + col] = v[r];
    };

    // resident conv biases (per-lane, feature = nt*16+col)
    float bp1v[4], b1v[4], bp2v[4], b2v[4];
    #pragma unroll
    for (int nt = 0; nt < 4; ++nt) {
        bp1v[nt] = bp1[nt * 16 + col];
        b1v[nt]  = b1[nt * 16 + col];
        bp2v[nt] = bp2[nt * 16 + col];
        b2v[nt]  = b2[nt * 16 + col];
    }
    const float mb4v = (col < 10) ? Mb4[col & 1] : Mb4[2 + (col & 1)];

    const int wid = blockIdx.x * NW + w;

    for (int b = 0; b < NB; ++b) {
        const int g0 = (wid * NB + b) * 16;

        // ---- obs A-frags: Mtile a = agent, row m = col = group ----
        half8_t Aobs[6][2];
        const float* orow = obs + ((size_t)(g0 + col) * 6) * 64 + quad * 8;
        #pragma unroll
        for (int a = 0; a < 6; ++a) {
            #pragma unroll
            for (int kf = 0; kf < 2; ++kf) {
                const float4_t x = *(const float4_t*)(orow + a * 64 + kf * 32);
                const float4_t y = *(const float4_t*)(orow + a * 64 + kf * 32 + 4);
                half8_t r;
                r[0] = (f16)x[0]; r[1] = (f16)x[1]; r[2] = (f16)x[2]; r[3] = (f16)x[3];
                r[4] = (f16)y[0]; r[5] = (f16)y[1]; r[6] = (f16)y[2]; r[7] = (f16)y[3];
                Aobs[a][kf] = r;
            }
        }

        // ---- conv1 pool: n1 = max_a relu(obs_a @ Wp1 + bp1) ----
        half8_t B0[4][2];
        #pragma unroll
        for (int nt = 0; nt < 4; ++nt)
            #pragma unroll
            for (int kf = 0; kf < 2; ++kf) B0[nt][kf] = loadB(0 * 4096, nt, kf);
        float4_t n1[4];
        #pragma unroll
        for (int nt = 0; nt < 4; ++nt) n1[nt] = bcast4(0.f);
        #pragma unroll
        for (int a = 0; a < 6; ++a) {
            #pragma unroll
            for (int nt = 0; nt < 4; ++nt) {
                float4_t acc = bcast4(bp1v[nt]);
                acc = __builtin_amdgcn_mfma_f32_16x16x32_f16(Aobs[a][0], B0[nt][0], acc, 0, 0, 0);
                acc = __builtin_amdgcn_mfma_f32_16x16x32_f16(Aobs[a][1], B0[nt][1], acc, 0, 0, 0);
                n1[nt] = max4(n1[nt], acc);     // relu folded (init 0)
            }
        }

        // ---- c = n1 @ Wn1 + b1 (M=16 via slab round-trip) ----
        #pragma unroll
        for (int nt = 0; nt < 4; ++nt) storeC(n1[nt], nt);
        {
            const half8_t a0 = loadA(0), a1 = loadA(1);
            #pragma unroll
            for (int nt = 0; nt < 4; ++nt) {
                float4_t acc = bcast4(b1v[nt]);
                acc = __builtin_amdgcn_mfma_f32_16x16x32_f16(a0, loadB(2 * 4096, nt, 0), acc, 0, 0, 0);
                acc = __builtin_amdgcn_mfma_f32_16x16x32_f16(a1, loadB(2 * 4096, nt, 1), acc, 0, 0, 0);
                n1[nt] = acc;                    // reuse n1 regs as c
            }
        }

        // ---- per agent: h_a = tanh(obs_a@Ws1 + c); hbar += h; n2 = max relu(h_a@Wp2+bp2) ----
        half8_t B1[4][2], B3[4][2];
        #pragma unroll
        for (int nt = 0; nt < 4; ++nt)
            #pragma unroll
            for (int kf = 0; kf < 2; ++kf) {
                B1[nt][kf] = loadB(1 * 4096, nt, kf);
                B3[nt][kf] = loadB(3 * 4096, nt, kf);
            }
        float4_t hbar[4], n2[4];
        #pragma unroll
        for (int nt = 0; nt < 4; ++nt) { hbar[nt] = bcast4(0.f); n2[nt] = bcast4(0.f); }
        #pragma unroll
        for (int a = 0; a < 6; ++a) {
            #pragma unroll
            for (int nt = 0; nt < 4; ++nt) {
                float4_t acc = n1[nt];           // c
                acc = __builtin_amdgcn_mfma_f32_16x16x32_f16(Aobs[a][0], B1[nt][0], acc, 0, 0, 0);
                acc = __builtin_amdgcn_mfma_f32_16x16x32_f16(Aobs[a][1], B1[nt][1], acc, 0, 0, 0);
                #pragma unroll
                for (int r = 0; r < 4; ++r) acc[r] = fast_tanh(acc[r]);
                hbar[nt] += acc;
                storeC(acc, nt);
            }
            const half8_t ha0 = loadA(0), ha1 = loadA(1);
            #pragma unroll
            for (int nt = 0; nt < 4; ++nt) {
                float4_t q = bcast4(bp2v[nt]);
                q = __builtin_amdgcn_mfma_f32_16x16x32_f16(ha0, B3[nt][0], q, 0, 0, 0);
                q = __builtin_amdgcn_mfma_f32_16x16x32_f16(ha1, B3[nt][1], q, 0, 0, 0);
                n2[nt] = max4(n2[nt], q);
            }
        }
        #pragma unroll
        for (int nt = 0; nt < 4; ++nt) hbar[nt] *= (1.0f / 6.0f);

        // ---- res = hbar @ Ws2 + n2 @ Wn2 + b2 ----
        float4_t rres[4];
        #pragma unroll
        for (int nt = 0; nt < 4; ++nt) storeC(hbar[nt], nt);
        {
            const half8_t a0 = loadA(0), a1 = loadA(1);
            #pragma unroll
            for (int nt = 0; nt < 4; ++nt) {
                float4_t acc = bcast4(b2v[nt]);
                acc = __builtin_amdgcn_mfma_f32_16x16x32_f16(a0, loadB(4 * 4096, nt, 0), acc, 0, 0, 0);
                acc = __builtin_amdgcn_mfma_f32_16x16x32_f16(a1, loadB(4 * 4096, nt, 1), acc, 0, 0, 0);
                rres[nt] = acc;
            }
        }
        #pragma unroll
        for (int nt = 0; nt < 4; ++nt) storeC(n2[nt], nt);
        {
            const half8_t a0 = loadA(0), a1 = loadA(1);
            #pragma unroll
            for (int nt = 0; nt < 4; ++nt) {
                rres[nt] = __builtin_amdgcn_mfma_f32_16x16x32_f16(a0, loadB(5 * 4096, nt, 0), rres[nt], 0, 0, 0);
                rres[nt] = __builtin_amdgcn_mfma_f32_16x16x32_f16(a1, loadB(5 * 4096, nt, 1), rres[nt], 0, 0, 0);
            }
        }

        // ---- per-type 3-layer relu MLP; keep x3 A-frags for the head ----
        half8_t x3f[2][2];
        #pragma unroll
        for (int ty = 0; ty < 2; ++ty) {
            #pragma unroll
            for (int nt = 0; nt < 4; ++nt) storeC(rres[nt], nt);
            half8_t xa0 = loadA(0), xa1 = loadA(1);
            #pragma unroll
            for (int layer = 0; layer < 3; ++layer) {
                const int baseH = (6 + ty * 3 + layer) * 4096;
                const float* Mb = (layer == 0 ? Mb1 : layer == 1 ? Mb2 : Mb3) + ty * 64;
                #pragma unroll
                for (int nt = 0; nt < 4; ++nt) {
                    float4_t acc = bcast4(Mb[nt * 16 + col]);
                    acc = __builtin_amdgcn_mfma_f32_16x16x32_f16(xa0, loadB(baseH, nt, 0), acc, 0, 0, 0);
                    acc = __builtin_amdgcn_mfma_f32_16x16x32_f16(xa1, loadB(baseH, nt, 1), acc, 0, 0, 0);
                    acc = max4(acc, bcast4(0.f));   // relu
                    storeC(acc, nt);
                }
                xa0 = loadA(0); xa1 = loadA(1);
            }
            x3f[ty][0] = xa0; x3f[ty][1] = xa1;
        }

        // ---- head: one chained MFMA pair per type; D cols 0..11 = out[g][:] ----
        float4_t d = bcast4(0.f);
        d = __builtin_amdgcn_mfma_f32_16x16x32_f16(x3f[0][0], loadB(12 * 4096, 0, 0), d, 0, 0, 0);
        d = __builtin_amdgcn_mfma_f32_16x16x32_f16(x3f[0][1], loadB(12 * 4096, 0, 1), d, 0, 0, 0);
        d = __builtin_amdgcn_mfma_f32_16x16x32_f16(x3f[1][0], loadB(12 * 4096 + 1024, 0, 0), d, 0, 0, 0);
        d = __builtin_amdgcn_mfma_f32_16x16x32_f16(x3f[1][1], loadB(12 * 4096 + 1024, 0, 1), d, 0, 0, 0);

        if (col < 12) {
            #pragma unroll
            for (int r = 0; r < 4; ++r) {
                const float v = fast_tanh(d[r] + mb4v);
                out[(size_t)(g0 + quad * 4 + r) * 12 + col] = v;
            }
        }
    }
}

extern "C" void kernel_launch(void* const* d_in, const int* in_sizes, int n_in,
                              void* d_out, int out_size, void* d_ws, size_t ws_size,
                              hipStream_t stream)
{
    const float* obs = (const float*)d_in[0];
    const float* Wp1 = (const float*)d_in[1];
    const float* bp1 = (const float*)d_in[2];
    const float* Ws1 = (const float*)d_in[3];
    const float* Wn1 = (const float*)d_in[4];
    const float* b1  = (const float*)d_in[5];
    const float* Wp2 = (const float*)d_in[6];
    const float* bp2 = (const float*)d_in[7];
    const float* Ws2 = (const float*)d_in[8];
    const float* Wn2 = (const float*)d_in[9];
    const float* b2  = (const float*)d_in[10];
    const float* MW1 = (const float*)d_in[11];
    const float* Mb1 = (const float*)d_in[12];
    const float* MW2 = (const float*)d_in[13];
    const float* Mb2 = (const float*)d_in[14];
    const float* MW3 = (const float*)d_in[15];
    const float* Mb3 = (const float*)d_in[16];
    const float* MW4 = (const float*)d_in[17];
    const float* Mb4 = (const float*)d_in[18];
    float* out = (float*)d_out;
    f16* img = (f16*)d_ws;   // 51200 halfs = 100 KB

    hipLaunchKernelGGL(prep_weights, dim3(13), dim3(256), 0, stream,
                       Wp1, Ws1, Wn1, Wp2, Ws2, Wn2, MW1, MW2, MW3, MW4, img);
    // 256 blocks x 8 waves x NB=4 batches x 16 groups = 131072
    hipLaunchKernelGGL(gnn_mfma, dim3(256), dim3(512), 0, stream,
                       obs, img, bp1, b1, bp2, b2, Mb1, Mb2, Mb3, Mb4, out);
}